// Round 1
// baseline (8227.032 us; speedup 1.0000x reference)
//
#include <hip/hip_runtime.h>
#include <hip/hip_bf16.h>

#define B_ 64
#define S_ 64
#define T_ 64
#define E_ 256
#define U_ 512
#define V_ 32000
#define G4 2048  // 4*U

typedef __attribute__((ext_vector_type(8))) short bf16x8;
typedef __attribute__((ext_vector_type(4))) float f32x4;
typedef __attribute__((ext_vector_type(4))) unsigned short u16x4;
typedef unsigned short u16;

typedef __attribute__((address_space(3))) unsigned int as3_u32;
typedef const __attribute__((address_space(1))) unsigned int as1_u32;

__device__ inline u16 f2b(float v) {
    __hip_bfloat16 h = __float2bfloat16(v);
    return __builtin_bit_cast(unsigned short, h);
}

__device__ inline float sigm(float x) { return 1.0f / (1.0f + __expf(-x)); }
__device__ inline float tanh_fast(float x) {
    float e = __expf(2.0f * x);
    return 1.0f - 2.0f / (e + 1.0f);
}

// ---------------- prep kernels ----------------

__global__ __launch_bounds__(256) void k_cvt_bf16(const float* __restrict__ in,
                                                  u16* __restrict__ out, int n8) {
    int i = blockIdx.x * blockDim.x + threadIdx.x;
    if (i >= n8) return;
    const float4* in4 = (const float4*)in;
    float4 a = in4[i * 2];
    float4 b = in4[i * 2 + 1];
    bf16x8 v;
    v[0] = (short)f2b(a.x); v[1] = (short)f2b(a.y);
    v[2] = (short)f2b(a.z); v[3] = (short)f2b(a.w);
    v[4] = (short)f2b(b.x); v[5] = (short)f2b(b.y);
    v[6] = (short)f2b(b.z); v[7] = (short)f2b(b.w);
    *(bf16x8*)(out + (size_t)i * 8) = v;
}

__global__ __launch_bounds__(256) void k_bias(const float* __restrict__ a,
                                              const float* __restrict__ b,
                                              float* __restrict__ o, int n) {
    int i = blockIdx.x * blockDim.x + threadIdx.x;
    if (i < n) o[i] = a[i] + b[i];
}

// one block per output row r = t*64 + b; copies emb[token] -> out[r] as bf16
__global__ __launch_bounds__(64) void k_gather(const float* __restrict__ emb,
                                               const int* __restrict__ tok,
                                               int tok_stride, u16* __restrict__ out) {
    int r = blockIdx.x;
    int t = r >> 6, b = r & 63;
    int token = tok[b * tok_stride + t];
    const float4* src = (const float4*)(emb + (size_t)token * E_);
    int i = threadIdx.x;  // 64 threads, 4 f32 each
    float4 v = src[i];
    u16x4 o4;
    o4[0] = f2b(v.x); o4[1] = f2b(v.y); o4[2] = f2b(v.z); o4[3] = f2b(v.w);
    *(u16x4*)(out + (size_t)r * E_ + i * 4) = o4;
}

// ---------------- bf16 MFMA GEMM: C[M][N] = A[M][K] @ Bm[N][K]^T + bias[N] ----------------
// 128x128 tile, BK=32, 256 threads (4 waves, each 64x64), global_load_lds staging.
// remap=1: output row r -> ((r&63)<<6)|(r>>6)   (hs (t,b) order -> logits (b,t) order)

__global__ __launch_bounds__(256) void k_gemm(const u16* __restrict__ A,
                                              const u16* __restrict__ Bm,
                                              const float* __restrict__ bias,
                                              float* __restrict__ C,
                                              int M, int N, int K, int Mt, int remap) {
    __shared__ u16 As[128 * 32];
    __shared__ u16 Bs[128 * 32];

    int bid = blockIdx.x;
    int bm = bid % Mt, bn = bid / Mt;
    int tid = threadIdx.x;
    int lane = tid & 63;
    int w = tid >> 6;
    int wr = (w >> 1) * 64, wc = (w & 1) * 64;

    f32x4 acc[4][4] = {};

    const long row0 = (long)bm * 128;
    const long col0 = (long)bn * 128;

    int r_a = tid >> 2;          // row within 64-row chunk
    int kb = (tid & 3) * 16;     // byte offset within 64B k-chunk

    int nK = K / 32;
    for (int ks = 0; ks < nK; ++ks) {
        long kbyte = (long)ks * 64;  // 32 bf16 = 64 bytes
        const char* a0 = (const char*)(A + (row0 + r_a) * (long)K) + kbyte + kb;
        const char* a1 = (const char*)(A + (row0 + 64 + r_a) * (long)K) + kbyte + kb;
        const char* b0 = (const char*)(Bm + (col0 + r_a) * (long)K) + kbyte + kb;
        const char* b1 = (const char*)(Bm + (col0 + 64 + r_a) * (long)K) + kbyte + kb;
        __builtin_amdgcn_global_load_lds((as1_u32*)a0, (as3_u32*)((char*)As + tid * 16), 16, 0, 0);
        __builtin_amdgcn_global_load_lds((as1_u32*)a1, (as3_u32*)((char*)As + 4096 + tid * 16), 16, 0, 0);
        __builtin_amdgcn_global_load_lds((as1_u32*)b0, (as3_u32*)((char*)Bs + tid * 16), 16, 0, 0);
        __builtin_amdgcn_global_load_lds((as1_u32*)b1, (as3_u32*)((char*)Bs + 4096 + tid * 16), 16, 0, 0);
        __syncthreads();

        int lr = lane & 15;
        int lk = (lane >> 4) * 8;
        bf16x8 af[4], bfr[4];
#pragma unroll
        for (int mi = 0; mi < 4; ++mi)
            af[mi] = *(const bf16x8*)&As[(wr + mi * 16 + lr) * 32 + lk];
#pragma unroll
        for (int ni = 0; ni < 4; ++ni)
            bfr[ni] = *(const bf16x8*)&Bs[(wc + ni * 16 + lr) * 32 + lk];
#pragma unroll
        for (int mi = 0; mi < 4; ++mi)
#pragma unroll
            for (int ni = 0; ni < 4; ++ni)
                acc[mi][ni] = __builtin_amdgcn_mfma_f32_16x16x32_bf16(af[mi], bfr[ni], acc[mi][ni], 0, 0, 0);
        __syncthreads();
    }

    // epilogue: D col = lane&15, row = (lane>>4)*4 + q
    int lr = lane & 15;
    int lq = (lane >> 4) * 4;
#pragma unroll
    for (int mi = 0; mi < 4; ++mi) {
#pragma unroll
        for (int q = 0; q < 4; ++q) {
            long r = row0 + wr + mi * 16 + lq + q;
            long rr = remap ? (((r & 63) << 6) | (r >> 6)) : r;
            float* crow = C + rr * (long)N + col0 + wc;
#pragma unroll
            for (int ni = 0; ni < 4; ++ni) {
                int cc = ni * 16 + lr;
                crow[cc] = acc[mi][ni][q] + bias[col0 + wc + cc];
            }
        }
    }
}

// ---------------- LSTM step: gates = Xg[t] + h @ Whh^T; update h,c ----------------
// grid: 128 blocks (4 b-tiles x 32 u-tiles), 256 threads; thread = (b_local, u_local)

__global__ __launch_bounds__(256) void k_step(const float* __restrict__ Xg,   // [64][2048]
                                              const float* __restrict__ Whh,  // [2048][512]
                                              float* __restrict__ h, float* __restrict__ c,
                                              u16* __restrict__ hs_out,       // [64][512] bf16 or null
                                              int first) {
    __shared__ float hsh[16][512];
    int blk = blockIdx.x;
    int btile = blk & 3, utile = blk >> 2;
    int tid = threadIdx.x;
    int ul = tid & 15, bl = tid >> 4;
    int b = btile * 16 + bl;
    int u = utile * 16 + ul;

    if (!first) {
        const float4* hg = (const float4*)(h + (size_t)btile * 16 * U_);
        float4* hl = (float4*)&hsh[0][0];
#pragma unroll
        for (int i = 0; i < 8; ++i)
            hl[tid + i * 256] = hg[tid + i * 256];
    }
    __syncthreads();

    float xi = Xg[b * G4 + u];
    float xf = Xg[b * G4 + 512 + u];
    float xg = Xg[b * G4 + 1024 + u];
    float xo = Xg[b * G4 + 1536 + u];

    if (!first) {
        const float4* wi = (const float4*)(Whh + (size_t)u * U_);
        const float4* wf = (const float4*)(Whh + (size_t)(512 + u) * U_);
        const float4* wg = (const float4*)(Whh + (size_t)(1024 + u) * U_);
        const float4* wo = (const float4*)(Whh + (size_t)(1536 + u) * U_);
        const float4* hv4 = (const float4*)&hsh[bl][0];
        float ai = 0.f, afv = 0.f, agv = 0.f, aov = 0.f;
#pragma unroll 4
        for (int k4 = 0; k4 < 128; ++k4) {
            float4 hv = hv4[k4];
            float4 A = wi[k4], B = wf[k4], Cc = wg[k4], D = wo[k4];
            ai  += hv.x * A.x + hv.y * A.y + hv.z * A.z + hv.w * A.w;
            afv += hv.x * B.x + hv.y * B.y + hv.z * B.z + hv.w * B.w;
            agv += hv.x * Cc.x + hv.y * Cc.y + hv.z * Cc.z + hv.w * Cc.w;
            aov += hv.x * D.x + hv.y * D.y + hv.z * D.z + hv.w * D.w;
        }
        xi += ai; xf += afv; xg += agv; xo += aov;
    }

    float cp = first ? 0.0f : c[b * U_ + u];
    float ig = sigm(xi), fg = sigm(xf), gg = tanh_fast(xg), og = sigm(xo);
    float cn = fg * cp + ig * gg;
    float hn = og * tanh_fast(cn);
    c[b * U_ + u] = cn;
    h[b * U_ + u] = hn;
    if (hs_out) hs_out[b * U_ + u] = f2b(hn);
}

// ---------------- launch ----------------

extern "C" void kernel_launch(void* const* d_in, const int* in_sizes, int n_in,
                              void* d_out, int out_size, void* d_ws, size_t ws_size,
                              hipStream_t stream) {
    const int*   x       = (const int*)  d_in[0];
    const int*   y       = (const int*)  d_in[1];
    const float* enc_emb = (const float*)d_in[2];
    const float* enc_Wih = (const float*)d_in[3];
    const float* enc_Whh = (const float*)d_in[4];
    const float* enc_bih = (const float*)d_in[5];
    const float* enc_bhh = (const float*)d_in[6];
    const float* dec_emb = (const float*)d_in[7];
    const float* dec_Wih = (const float*)d_in[8];
    const float* dec_Whh = (const float*)d_in[9];
    const float* dec_bih = (const float*)d_in[10];
    const float* dec_bhh = (const float*)d_in[11];
    const float* out_W   = (const float*)d_in[12];
    const float* out_b   = (const float*)d_in[13];
    float* out = (float*)d_out;

    char* ws = (char*)d_ws;
    size_t off = 0;
    auto alloc = [&](size_t bytes) -> char* {
        char* p = ws + off;
        off = (off + bytes + 255) & ~(size_t)255;
        return p;
    };
    u16*   WihE = (u16*)alloc((size_t)G4 * E_ * 2);
    u16*   WihD = (u16*)alloc((size_t)G4 * E_ * 2);
    u16*   OW   = (u16*)alloc((size_t)V_ * U_ * 2);
    u16*   XeE  = (u16*)alloc((size_t)S_ * B_ * E_ * 2);
    u16*   XeD  = (u16*)alloc((size_t)T_ * B_ * E_ * 2);
    float* bcE  = (float*)alloc(G4 * 4);
    float* bcD  = (float*)alloc(G4 * 4);
    float* XgE  = (float*)alloc((size_t)S_ * B_ * G4 * 4);
    float* XgD  = (float*)alloc((size_t)T_ * B_ * G4 * 4);
    float* hbuf = (float*)alloc((size_t)B_ * U_ * 4);
    float* cbuf = (float*)alloc((size_t)B_ * U_ * 4);
    u16*   HS   = (u16*)alloc((size_t)T_ * B_ * U_ * 2);
    (void)ws_size; (void)in_sizes; (void)n_in; (void)out_size;

    // weight/bias/embedding prep
    int n8_ih = G4 * E_ / 8;
    k_cvt_bf16<<<(n8_ih + 255) / 256, 256, 0, stream>>>(enc_Wih, WihE, n8_ih);
    k_cvt_bf16<<<(n8_ih + 255) / 256, 256, 0, stream>>>(dec_Wih, WihD, n8_ih);
    int n8_ow = V_ * U_ / 8;
    k_cvt_bf16<<<(n8_ow + 255) / 256, 256, 0, stream>>>(out_W, OW, n8_ow);
    k_bias<<<(G4 + 255) / 256, 256, 0, stream>>>(enc_bih, enc_bhh, bcE, G4);
    k_bias<<<(G4 + 255) / 256, 256, 0, stream>>>(dec_bih, dec_bhh, bcD, G4);
    k_gather<<<S_ * B_, 64, 0, stream>>>(enc_emb, x, S_, XeE);
    k_gather<<<T_ * B_, 64, 0, stream>>>(dec_emb, y, T_ + 1, XeD);

    // input projections: Xg = Xe @ Wih^T + (bih+bhh)
    k_gemm<<<32 * 16, 256, 0, stream>>>(XeE, WihE, bcE, XgE, 4096, G4, E_, 32, 0);
    k_gemm<<<32 * 16, 256, 0, stream>>>(XeD, WihD, bcD, XgD, 4096, G4, E_, 32, 0);

    // recurrence
    for (int t = 0; t < S_; ++t)
        k_step<<<128, 256, 0, stream>>>(XgE + (size_t)t * B_ * G4, enc_Whh, hbuf, cbuf,
                                        (u16*)nullptr, t == 0);
    for (int t = 0; t < T_; ++t)
        k_step<<<128, 256, 0, stream>>>(XgD + (size_t)t * B_ * G4, dec_Whh, hbuf, cbuf,
                                        HS + (size_t)t * B_ * U_, 0);

    // logits = hs @ out_W^T + out_b   (remap rows (t,b)->(b,t))
    k_gemm<<<32 * 250, 256, 0, stream>>>(HS, OW, out_b, out, 4096, V_, U_, 32, 1);
}